// Round 2
// baseline (69416.132 us; speedup 1.0000x reference)
//
#include <hip/hip_runtime.h>

// All inputs/outputs are float32 (per reference setup_inputs / return dtype).

// ---------------- RMSNorm (fp32 in, fp32 out) ----------------
__global__ __launch_bounds__(256) void rmsnorm_f32(const float* __restrict__ x,
                                                   const float* __restrict__ w,
                                                   float* __restrict__ out, int cols) {
    int row = blockIdx.x;
    const float* xr = x + (size_t)row * cols;
    float ss = 0.f;
    for (int c = threadIdx.x; c < cols; c += 256) { float v = xr[c]; ss += v * v; }
    __shared__ float red[256];
    red[threadIdx.x] = ss; __syncthreads();
    for (int s = 128; s > 0; s >>= 1) {
        if ((int)threadIdx.x < s) red[threadIdx.x] += red[threadIdx.x + s];
        __syncthreads();
    }
    float scale = rsqrtf(red[0] / (float)cols + 1e-6f);
    float* orow = out + (size_t)row * cols;
    for (int c = threadIdx.x; c < cols; c += 256) orow[c] = xr[c] * scale * w[c];
}

// ---------------- GEMM: C[M,N] = A[M,K] @ B[N,K]^T (+ optional f32 residual) ----------------
__global__ __launch_bounds__(256) void gemm_abt(const float* __restrict__ A,
                                                const float* __restrict__ B,
                                                float* __restrict__ C,
                                                int M, int N, int Kd,
                                                const float* __restrict__ residual) {
    __shared__ float As[16][64];
    __shared__ float Bs[16][64];
    int bm = blockIdx.y * 64;
    int bn = blockIdx.x * 64;
    int tid = threadIdx.x;
    int tcol = tid & 15, trow = tid >> 4;
    float acc[4][4] = {{0.f}};
    for (int k0 = 0; k0 < Kd; k0 += 16) {
        #pragma unroll
        for (int l = 0; l < 4; ++l) {
            int e = tid + l * 256;
            int m = e >> 4, kk = e & 15;
            As[kk][m] = A[(size_t)(bm + m) * Kd + k0 + kk];
        }
        #pragma unroll
        for (int l = 0; l < 4; ++l) {
            int e = tid + l * 256;
            int n = e >> 4, kk = e & 15;
            int gn = bn + n;
            Bs[kk][n] = (gn < N) ? B[(size_t)gn * Kd + k0 + kk] : 0.f;
        }
        __syncthreads();
        #pragma unroll
        for (int kk = 0; kk < 16; ++kk) {
            float4 a4 = *reinterpret_cast<const float4*>(&As[kk][trow * 4]);
            float4 b4 = *reinterpret_cast<const float4*>(&Bs[kk][tcol * 4]);
            float a[4] = {a4.x, a4.y, a4.z, a4.w};
            float b[4] = {b4.x, b4.y, b4.z, b4.w};
            #pragma unroll
            for (int i = 0; i < 4; ++i)
                #pragma unroll
                for (int j = 0; j < 4; ++j) acc[i][j] += a[i] * b[j];
        }
        __syncthreads();
    }
    #pragma unroll
    for (int i = 0; i < 4; ++i) {
        int m = bm + trow * 4 + i;
        #pragma unroll
        for (int j = 0; j < 4; ++j) {
            int n = bn + tcol * 4 + j;
            if (n < N) {
                float v = acc[i][j];
                if (residual) v += residual[(size_t)m * N + n];
                C[(size_t)m * N + n] = v;
            }
        }
    }
}

// ---------------- RoPE in-place: qfull[T,16,192] & kvfull[T,16,320], dims 128..191 ----------------
__global__ __launch_bounds__(256) void rope_kernel(float* __restrict__ qfull, float* __restrict__ kvfull, int T) {
    int idx = blockIdx.x * 256 + threadIdx.x;
    int total = T * 16 * 32;
    if (idx >= total) return;
    int i = idx & 31;
    int h = (idx >> 5) & 15;
    int t = idx >> 9;
    float invf = powf(10000.0f, -(float)(2 * i) / 64.0f);
    float ang = (float)t * invf;
    float c = cosf(ang), s = sinf(ang);   // precise: v_sin domain is only +-256 revolutions
    float* qr = qfull + (size_t)t * 3072 + h * 192 + 128;
    float x1 = qr[i], x2 = qr[i + 32];
    qr[i] = x1 * c - x2 * s;
    qr[i + 32] = x2 * c + x1 * s;
    float* kr = kvfull + (size_t)t * 5120 + h * 320 + 128;
    x1 = kr[i]; x2 = kr[i + 32];
    kr[i] = x1 * c - x2 * s;
    kr[i + 32] = x2 * c + x1 * s;
}

// ---------------- Attention: one block per (head, query-row), causal ----------------
__global__ __launch_bounds__(128) void attn_kernel(const float* __restrict__ qfull,
                                                   const float* __restrict__ kvfull,
                                                   float* __restrict__ ctx, int T) {
    int h = blockIdx.x & 15;
    int q = blockIdx.x >> 4;
    int tid = threadIdx.x; // 128
    __shared__ float qs[192];
    __shared__ float sc[2048];
    __shared__ float red[128];
    const float* qp = qfull + (size_t)q * 3072 + h * 192;
    for (int d = tid; d < 192; d += 128) qs[d] = qp[d];
    __syncthreads();
    int nk = q + 1;
    const float scale = 0.07216878364870322f; // 1/sqrt(192)
    float lmax = -1e30f;
    for (int k = tid; k < nk; k += 128) {
        const float4* kp4 = reinterpret_cast<const float4*>(kvfull + (size_t)k * 5120 + h * 320);
        float s = 0.f;
        #pragma unroll 8
        for (int d4 = 0; d4 < 48; ++d4) {
            float4 kv4 = kp4[d4];
            int d = d4 * 4;
            s += qs[d] * kv4.x + qs[d + 1] * kv4.y + qs[d + 2] * kv4.z + qs[d + 3] * kv4.w;
        }
        s *= scale;
        sc[k] = s;
        lmax = fmaxf(lmax, s);
    }
    red[tid] = lmax; __syncthreads();
    for (int s2 = 64; s2 > 0; s2 >>= 1) {
        if (tid < s2) red[tid] = fmaxf(red[tid], red[tid + s2]);
        __syncthreads();
    }
    float m = red[0];
    __syncthreads();
    float lsum = 0.f;
    for (int k = tid; k < nk; k += 128) { float p = __expf(sc[k] - m); sc[k] = p; lsum += p; }
    red[tid] = lsum; __syncthreads();
    for (int s2 = 64; s2 > 0; s2 >>= 1) {
        if (tid < s2) red[tid] += red[tid + s2];
        __syncthreads();
    }
    float inv = 1.0f / red[0];
    int d = tid; // DV=128
    float accv = 0.f;
    const float* vbase = kvfull + (size_t)h * 320 + 192 + d;
    for (int k = 0; k < nk; ++k) accv += sc[k] * vbase[(size_t)k * 5120];
    ctx[(size_t)q * 2048 + h * 128 + d] = accv * inv;
}

// ---------------- Router: sigmoid + top-4 + normalized weights * 2.5 ----------------
__global__ __launch_bounds__(256) void router_kernel(const float* __restrict__ h2,
                                                     const float* __restrict__ rw,
                                                     const float* __restrict__ rb,
                                                     int* __restrict__ topi, float* __restrict__ topw) {
    int t = blockIdx.x;
    int tid = threadIdx.x;
    int e = tid >> 4;
    int lane = tid & 15;
    const float* xr = h2 + (size_t)t * 2048;
    const float* wr = rw + (size_t)e * 2048;
    float partial = 0.f;
    for (int hh = lane; hh < 2048; hh += 16) partial += xr[hh] * wr[hh];
    __shared__ float red[256];
    __shared__ float probs[16];
    red[tid] = partial; __syncthreads();
    for (int s = 8; s > 0; s >>= 1) {
        if (lane < s) red[tid] += red[tid + s];
        __syncthreads();
    }
    if (lane == 0) {
        float logit = red[tid] + rb[e];
        probs[e] = 1.0f / (1.0f + __expf(-logit));
    }
    __syncthreads();
    if (tid == 0) {
        bool used[16] = {false};
        int idxs[4]; float vals[4]; float sum = 0.f;
        for (int k = 0; k < 4; ++k) {
            float best = -1e30f; int bi = 0;
            for (int ee = 0; ee < 16; ++ee)
                if (!used[ee] && probs[ee] > best) { best = probs[ee]; bi = ee; }
            used[bi] = true; idxs[k] = bi; vals[k] = best; sum += best;
        }
        float invs = 2.5f / (sum + 1e-9f);
        for (int k = 0; k < 4; ++k) { topi[t * 4 + k] = idxs[k]; topw[t * 4 + k] = vals[k] * invs; }
    }
}

// ---------------- MoE gate/up for selected experts; act = w * silu(g) * u ----------------
__global__ __launch_bounds__(256) void moe_gateup(const float* __restrict__ h2,
                                                  const float* __restrict__ gate_w,
                                                  const float* __restrict__ up_w,
                                                  const int* __restrict__ topi,
                                                  const float* __restrict__ topw,
                                                  float* __restrict__ act) {
    int pair = blockIdx.x; // t*4 + k
    int t = pair >> 2;
    int e = topi[pair];
    float w = topw[pair];
    __shared__ float xs[2048];
    for (int c = threadIdx.x; c < 2048; c += 256) xs[c] = h2[(size_t)t * 2048 + c];
    __syncthreads();
    const float* gbase = gate_w + (size_t)e * 1024 * 2048;
    const float* ubase = up_w + (size_t)e * 1024 * 2048;
    for (int m = threadIdx.x; m < 1024; m += 256) {
        const float4* gr = reinterpret_cast<const float4*>(gbase + (size_t)m * 2048);
        const float4* ur = reinterpret_cast<const float4*>(ubase + (size_t)m * 2048);
        float g = 0.f, u = 0.f;
        for (int c4 = 0; c4 < 512; ++c4) {
            float4 gw = gr[c4], uw = ur[c4];
            int c = c4 * 4;
            g += xs[c] * gw.x + xs[c + 1] * gw.y + xs[c + 2] * gw.z + xs[c + 3] * gw.w;
            u += xs[c] * uw.x + xs[c + 1] * uw.y + xs[c + 2] * uw.z + xs[c + 3] * uw.w;
        }
        float silu = g / (1.0f + __expf(-g));
        act[(size_t)pair * 1024 + m] = w * silu * u;
    }
}

// ---------------- shared expert activation: ash = silu(sg) * su ----------------
__global__ __launch_bounds__(256) void silu_mul(const float* __restrict__ g, const float* __restrict__ u,
                                                float* __restrict__ o, int n) {
    int i = blockIdx.x * 256 + threadIdx.x;
    if (i < n) { float gv = g[i]; o[i] = gv / (1.0f + __expf(-gv)) * u[i]; }
}

// ---------------- Fused: out = x2 + routed_down + shared_down ----------------
__global__ __launch_bounds__(256) void moe_down_final(const float* __restrict__ x2,
                                                      const float* __restrict__ act,
                                                      const float* __restrict__ ash,
                                                      const float* __restrict__ down_w,
                                                      const float* __restrict__ sd_w,
                                                      const int* __restrict__ topi,
                                                      float* __restrict__ out) {
    int t = blockIdx.x;
    __shared__ float a_s[4][1024];
    __shared__ float sh_s[1024];
    __shared__ int es[4];
    for (int m = threadIdx.x; m < 1024; m += 256) {
        #pragma unroll
        for (int k = 0; k < 4; ++k) a_s[k][m] = act[((size_t)t * 4 + k) * 1024 + m];
        sh_s[m] = ash[(size_t)t * 1024 + m];
    }
    if (threadIdx.x < 4) es[threadIdx.x] = topi[t * 4 + threadIdx.x];
    __syncthreads();
    for (int hh = threadIdx.x; hh < 2048; hh += 256) {
        float acc = x2[(size_t)t * 2048 + hh];
        #pragma unroll
        for (int k = 0; k < 4; ++k) {
            const float4* dr = reinterpret_cast<const float4*>(down_w + ((size_t)es[k] * 2048 + hh) * 1024);
            float s = 0.f;
            for (int m4 = 0; m4 < 256; ++m4) {
                float4 dw = dr[m4];
                int m = m4 * 4;
                s += a_s[k][m] * dw.x + a_s[k][m + 1] * dw.y + a_s[k][m + 2] * dw.z + a_s[k][m + 3] * dw.w;
            }
            acc += s;
        }
        const float4* sr = reinterpret_cast<const float4*>(sd_w + (size_t)hh * 1024);
        float s = 0.f;
        for (int m4 = 0; m4 < 256; ++m4) {
            float4 dw = sr[m4];
            int m = m4 * 4;
            s += sh_s[m] * dw.x + sh_s[m + 1] * dw.y + sh_s[m + 2] * dw.z + sh_s[m + 3] * dw.w;
        }
        acc += s;
        out[(size_t)t * 2048 + hh] = acc;
    }
}

// ---------------- launch ----------------
extern "C" void kernel_launch(void* const* d_in, const int* in_sizes, int n_in,
                              void* d_out, int out_size, void* d_ws, size_t ws_size,
                              hipStream_t stream) {
    (void)in_sizes; (void)n_in; (void)out_size; (void)ws_size;
    const float* x        = (const float*)d_in[0];
    // d_in[1] attention_mask: exactly causal 0/-1e9 — implied by loop bounds, unused.
    const float* ln1_w    = (const float*)d_in[2];
    const float* ln2_w    = (const float*)d_in[3];
    const float* q_a_w    = (const float*)d_in[4];
    const float* q_a_ln   = (const float*)d_in[5];
    const float* q_b_w    = (const float*)d_in[6];
    const float* kv_a_w   = (const float*)d_in[7];
    const float* kv_a_ln  = (const float*)d_in[8];
    const float* kv_b_w   = (const float*)d_in[9];
    const float* o_w      = (const float*)d_in[10];
    const float* router_w = (const float*)d_in[11];
    const float* router_b = (const float*)d_in[12];
    const float* gate_w   = (const float*)d_in[13];
    const float* up_w     = (const float*)d_in[14];
    const float* down_w   = (const float*)d_in[15];
    const float* sg_w     = (const float*)d_in[16];
    const float* su_w     = (const float*)d_in[17];
    const float* sd_w     = (const float*)d_in[18];

    const size_t T = 2048;
    float* ws = (float*)d_ws;
    float* x2     = ws;                      // T*2048
    float* h2     = x2 + T * 2048;           // T*2048
    float* h1     = h2 + T * 2048;           // T*2048 (reused as ctx after step 4)
    float* qa     = h1 + T * 2048;           // T*768
    float* kva    = qa + T * 768;            // T*512
    float* qfull  = kva + T * 512;           // T*3072
    float* kvfull = qfull + T * 3072;        // T*5120
    float* ctxb   = h1;                      // alias: h1 dead after q_a/kv_a GEMMs
    // MoE-phase aliases (attention intermediates dead):
    float* actb = qfull;                     // T*4096 (spills into kvfull region, which is dead)
    float* sg   = qfull + T * 4096;          // T*1024
    float* su   = sg + T * 1024;             // T*1024
    float* ash  = su + T * 1024;             // T*1024
    int*   topi = (int*)(ash + T * 1024);    // T*4
    float* topw = (float*)(topi + T * 4);    // T*4
    // total ws: T*15616 floats = 127.9 MB

    // 1) h1 = rmsnorm(x, ln1)
    rmsnorm_f32<<<T, 256, 0, stream>>>(x, ln1_w, h1, 2048);
    // 2) q_a / kv_a projections
    gemm_abt<<<dim3(768 / 64, T / 64), 256, 0, stream>>>(h1, q_a_w, qa, T, 768, 2048, nullptr);
    gemm_abt<<<dim3(512 / 64, T / 64), 256, 0, stream>>>(h1, kv_a_w, kva, T, 512, 2048, nullptr);
    // 3) lora rmsnorms (in-place)
    rmsnorm_f32<<<T, 256, 0, stream>>>(qa, q_a_ln, qa, 768);
    rmsnorm_f32<<<T, 256, 0, stream>>>(kva, kv_a_ln, kva, 512);
    // 4) up-projections
    gemm_abt<<<dim3(3072 / 64, T / 64), 256, 0, stream>>>(qa, q_b_w, qfull, T, 3072, 768, nullptr);
    gemm_abt<<<dim3(5120 / 64, T / 64), 256, 0, stream>>>(kva, kv_b_w, kvfull, T, 5120, 512, nullptr);
    // 5) RoPE in-place
    rope_kernel<<<(T * 16 * 32) / 256, 256, 0, stream>>>(qfull, kvfull, (int)T);
    // 6) causal attention
    attn_kernel<<<T * 16, 128, 0, stream>>>(qfull, kvfull, ctxb, (int)T);
    // 7) o-proj + residual -> x2
    gemm_abt<<<dim3(2048 / 64, T / 64), 256, 0, stream>>>(ctxb, o_w, x2, T, 2048, 2048, x);
    // 8) h2 = rmsnorm(x2, ln2)
    rmsnorm_f32<<<T, 256, 0, stream>>>(x2, ln2_w, h2, 2048);
    // 9) router -> top4 indices/weights
    router_kernel<<<T, 256, 0, stream>>>(h2, router_w, router_b, topi, topw);
    // 10) gate/up for the 4 selected experts per token
    moe_gateup<<<T * 4, 256, 0, stream>>>(h2, gate_w, up_w, topi, topw, actb);
    // 11) shared expert gate/up
    gemm_abt<<<dim3(1024 / 64, T / 64), 256, 0, stream>>>(h2, sg_w, sg, T, 1024, 2048, nullptr);
    gemm_abt<<<dim3(1024 / 64, T / 64), 256, 0, stream>>>(h2, su_w, su, T, 1024, 2048, nullptr);
    silu_mul<<<(T * 1024) / 256, 256, 0, stream>>>(sg, su, ash, (int)(T * 1024));
    // 12) fused down-proj (routed + shared) + residual -> out
    moe_down_final<<<T, 256, 0, stream>>>(x2, actb, ash, down_w, sd_w, topi, (float*)d_out);
}

// Round 3
// 7904.966 us; speedup vs baseline: 8.7813x; 8.7813x over previous
//
#include <hip/hip_runtime.h>

// ---------------- RMSNorm (fp32) ----------------
__global__ __launch_bounds__(256) void rmsnorm_f32(const float* __restrict__ x,
                                                   const float* __restrict__ w,
                                                   float* __restrict__ out, int cols) {
    int row = blockIdx.x;
    const float* xr = x + (size_t)row * cols;
    float ss = 0.f;
    for (int c = threadIdx.x; c < cols; c += 256) { float v = xr[c]; ss += v * v; }
    __shared__ float red[256];
    red[threadIdx.x] = ss; __syncthreads();
    for (int s = 128; s > 0; s >>= 1) {
        if ((int)threadIdx.x < s) red[threadIdx.x] += red[threadIdx.x + s];
        __syncthreads();
    }
    float scale = rsqrtf(red[0] / (float)cols + 1e-6f);
    float* orow = out + (size_t)row * cols;
    for (int c = threadIdx.x; c < cols; c += 256) orow[c] = xr[c] * scale * w[c];
}

// ---------------- Dense GEMM: C[M,N] = A[M,K] @ B[N,K]^T (+opt residual) ----------------
// 128x128 tile, 8x8 microtile. M,N multiples of 128; K multiple of 16.
__global__ __launch_bounds__(256) void gemm_abt128(const float* __restrict__ A,
                                                   const float* __restrict__ B,
                                                   float* __restrict__ C,
                                                   int N, int K,
                                                   const float* __restrict__ residual) {
    __shared__ float As[16][128];
    __shared__ float Bs[16][128];
    int bm = blockIdx.y * 128, bn = blockIdx.x * 128;
    int tid = threadIdx.x;
    int lrow = tid >> 1;            // 0..127
    int kk8 = (tid & 1) * 8;        // 0 or 8
    int trow = (tid >> 4) * 8;      // 0..120
    int tcol = (tid & 15) * 8;      // 0..120
    float acc[8][8] = {{0.f}};
    const float* Arow = A + (size_t)(bm + lrow) * K + kk8;
    const float* Brow = B + (size_t)(bn + lrow) * K + kk8;
    for (int k0 = 0; k0 < K; k0 += 16) {
        float4 av0 = *reinterpret_cast<const float4*>(Arow + k0);
        float4 av1 = *reinterpret_cast<const float4*>(Arow + k0 + 4);
        float4 bv0 = *reinterpret_cast<const float4*>(Brow + k0);
        float4 bv1 = *reinterpret_cast<const float4*>(Brow + k0 + 4);
        As[kk8 + 0][lrow] = av0.x; As[kk8 + 1][lrow] = av0.y;
        As[kk8 + 2][lrow] = av0.z; As[kk8 + 3][lrow] = av0.w;
        As[kk8 + 4][lrow] = av1.x; As[kk8 + 5][lrow] = av1.y;
        As[kk8 + 6][lrow] = av1.z; As[kk8 + 7][lrow] = av1.w;
        Bs[kk8 + 0][lrow] = bv0.x; Bs[kk8 + 1][lrow] = bv0.y;
        Bs[kk8 + 2][lrow] = bv0.z; Bs[kk8 + 3][lrow] = bv0.w;
        Bs[kk8 + 4][lrow] = bv1.x; Bs[kk8 + 5][lrow] = bv1.y;
        Bs[kk8 + 6][lrow] = bv1.z; Bs[kk8 + 7][lrow] = bv1.w;
        __syncthreads();
        #pragma unroll
        for (int kk = 0; kk < 16; ++kk) {
            float a[8], b[8];
            *reinterpret_cast<float4*>(&a[0]) = *reinterpret_cast<const float4*>(&As[kk][trow]);
            *reinterpret_cast<float4*>(&a[4]) = *reinterpret_cast<const float4*>(&As[kk][trow + 4]);
            *reinterpret_cast<float4*>(&b[0]) = *reinterpret_cast<const float4*>(&Bs[kk][tcol]);
            *reinterpret_cast<float4*>(&b[4]) = *reinterpret_cast<const float4*>(&Bs[kk][tcol + 4]);
            #pragma unroll
            for (int i = 0; i < 8; ++i)
                #pragma unroll
                for (int j = 0; j < 8; ++j) acc[i][j] += a[i] * b[j];
        }
        __syncthreads();
    }
    #pragma unroll
    for (int i = 0; i < 8; ++i) {
        size_t m = bm + trow + i;
        float* crow = C + m * N + bn + tcol;
        if (residual) {
            const float* rrow = residual + m * N + bn + tcol;
            #pragma unroll
            for (int j = 0; j < 8; ++j) crow[j] = acc[i][j] + rrow[j];
        } else {
            #pragma unroll
            for (int j = 0; j < 8; ++j) crow[j] = acc[i][j];
        }
    }
}

// ---------------- RoPE in-place ----------------
__global__ __launch_bounds__(256) void rope_kernel(float* __restrict__ qfull, float* __restrict__ kvfull, int T) {
    int idx = blockIdx.x * 256 + threadIdx.x;
    int total = T * 16 * 32;
    if (idx >= total) return;
    int i = idx & 31;
    int h = (idx >> 5) & 15;
    int t = idx >> 9;
    float invf = powf(10000.0f, -(float)(2 * i) / 64.0f);
    float ang = (float)t * invf;
    float c = cosf(ang), s = sinf(ang);
    float* qr = qfull + (size_t)t * 3072 + h * 192 + 128;
    float x1 = qr[i], x2 = qr[i + 32];
    qr[i] = x1 * c - x2 * s;
    qr[i + 32] = x2 * c + x1 * s;
    float* kr = kvfull + (size_t)t * 5120 + h * 320 + 128;
    x1 = kr[i]; x2 = kr[i + 32];
    kr[i] = x1 * c - x2 * s;
    kr[i + 32] = x2 * c + x1 * s;
}

// ---------------- Attention: one block per (head, query-row), causal ----------------
__global__ __launch_bounds__(128) void attn_kernel(const float* __restrict__ qfull,
                                                   const float* __restrict__ kvfull,
                                                   float* __restrict__ ctx, int T) {
    int h = blockIdx.x & 15;
    int q = blockIdx.x >> 4;
    int tid = threadIdx.x;
    __shared__ float qs[192];
    __shared__ float sc[2048];
    __shared__ float red[128];
    const float* qp = qfull + (size_t)q * 3072 + h * 192;
    for (int d = tid; d < 192; d += 128) qs[d] = qp[d];
    __syncthreads();
    int nk = q + 1;
    const float scale = 0.07216878364870322f; // 1/sqrt(192)
    float lmax = -1e30f;
    for (int k = tid; k < nk; k += 128) {
        const float4* kp4 = reinterpret_cast<const float4*>(kvfull + (size_t)k * 5120 + h * 320);
        float s = 0.f;
        #pragma unroll 8
        for (int d4 = 0; d4 < 48; ++d4) {
            float4 kv4 = kp4[d4];
            int d = d4 * 4;
            s += qs[d] * kv4.x + qs[d + 1] * kv4.y + qs[d + 2] * kv4.z + qs[d + 3] * kv4.w;
        }
        s *= scale;
        sc[k] = s;
        lmax = fmaxf(lmax, s);
    }
    red[tid] = lmax; __syncthreads();
    for (int s2 = 64; s2 > 0; s2 >>= 1) {
        if (tid < s2) red[tid] = fmaxf(red[tid], red[tid + s2]);
        __syncthreads();
    }
    float m = red[0];
    __syncthreads();
    float lsum = 0.f;
    for (int k = tid; k < nk; k += 128) { float p = __expf(sc[k] - m); sc[k] = p; lsum += p; }
    red[tid] = lsum; __syncthreads();
    for (int s2 = 64; s2 > 0; s2 >>= 1) {
        if (tid < s2) red[tid] += red[tid + s2];
        __syncthreads();
    }
    float inv = 1.0f / red[0];
    int d = tid;
    float accv = 0.f;
    const float* vbase = kvfull + (size_t)h * 320 + 192 + d;
    for (int k = 0; k < nk; ++k) accv += sc[k] * vbase[(size_t)k * 5120];
    ctx[(size_t)q * 2048 + h * 128 + d] = accv * inv;
}

// ---------------- Router: sigmoid + top-4 ----------------
__global__ __launch_bounds__(256) void router_kernel(const float* __restrict__ h2,
                                                     const float* __restrict__ rw,
                                                     const float* __restrict__ rb,
                                                     int* __restrict__ topi, float* __restrict__ topw) {
    int t = blockIdx.x;
    int tid = threadIdx.x;
    int e = tid >> 4;
    int lane = tid & 15;
    const float* xr = h2 + (size_t)t * 2048;
    const float* wr = rw + (size_t)e * 2048;
    float partial = 0.f;
    for (int hh = lane; hh < 2048; hh += 16) partial += xr[hh] * wr[hh];
    __shared__ float red[256];
    __shared__ float probs[16];
    red[tid] = partial; __syncthreads();
    for (int s = 8; s > 0; s >>= 1) {
        if (lane < s) red[tid] += red[tid + s];
        __syncthreads();
    }
    if (lane == 0) {
        float logit = red[tid] + rb[e];
        probs[e] = 1.0f / (1.0f + __expf(-logit));
    }
    __syncthreads();
    if (tid == 0) {
        bool used[16] = {false};
        int idxs[4]; float vals[4]; float sum = 0.f;
        for (int k = 0; k < 4; ++k) {
            float best = -1e30f; int bi = 0;
            for (int ee = 0; ee < 16; ++ee)
                if (!used[ee] && probs[ee] > best) { best = probs[ee]; bi = ee; }
            used[bi] = true; idxs[k] = bi; vals[k] = best; sum += best;
        }
        float invs = 2.5f / (sum + 1e-9f);
        for (int k = 0; k < 4; ++k) { topi[t * 4 + k] = idxs[k]; topw[t * 4 + k] = vals[k] * invs; }
    }
}

// ---------------- Bucket (token,expert) pairs by expert — single block ----------------
__global__ __launch_bounds__(256) void moe_bucket(const int* __restrict__ topi,
                                                  const float* __restrict__ topw,
                                                  int* __restrict__ btok, float* __restrict__ bw,
                                                  int* __restrict__ gcnt, int* __restrict__ goff) {
    __shared__ int cnt[16], off[16], cur[16];
    int tid = threadIdx.x;
    if (tid < 16) { cnt[tid] = 0; cur[tid] = 0; }
    __syncthreads();
    for (int p = tid; p < 8192; p += 256) atomicAdd(&cnt[topi[p]], 1);
    __syncthreads();
    if (tid == 0) { int s = 0; for (int e = 0; e < 16; ++e) { off[e] = s; s += cnt[e]; } }
    __syncthreads();
    for (int p = tid; p < 8192; p += 256) {
        int e = topi[p];
        int pos = off[e] + atomicAdd(&cur[e], 1);
        btok[pos] = p >> 2;
        bw[pos] = topw[p];
    }
    if (tid < 16) { gcnt[tid] = cnt[tid]; goff[tid] = off[tid]; }
}

// ---------------- Grouped gate/up GEMM: C[p,n] = h2[btok[p],:] @ W[e]^T ----------------
// W: [E, N, K] with N=1024, K=2048. grid = (N/128, 16 rowtiles, 16 experts)
__global__ __launch_bounds__(256) void moe_gemm_gu(const float* __restrict__ X,
                                                   const float* __restrict__ W,
                                                   float* __restrict__ C,
                                                   const int* __restrict__ btok,
                                                   const int* __restrict__ cnt,
                                                   const int* __restrict__ off,
                                                   int N, int K) {
    int e = blockIdx.z;
    int ce = cnt[e];
    int r0 = blockIdx.y * 128;
    if (r0 >= ce) return;
    int oe = off[e];
    __shared__ float As[16][128];
    __shared__ float Bs[16][128];
    int bn = blockIdx.x * 128;
    int tid = threadIdx.x;
    int lrow = tid >> 1;
    int kk8 = (tid & 1) * 8;
    int trow = (tid >> 4) * 8;
    int tcol = (tid & 15) * 8;
    int r = r0 + lrow;
    int rc = (r < ce) ? r : (ce - 1);
    int tok = btok[oe + rc];
    const float* Arow = X + (size_t)tok * K + kk8;
    const float* Brow = W + (size_t)e * N * K + (size_t)(bn + lrow) * K + kk8;
    float acc[8][8] = {{0.f}};
    for (int k0 = 0; k0 < K; k0 += 16) {
        float4 av0 = *reinterpret_cast<const float4*>(Arow + k0);
        float4 av1 = *reinterpret_cast<const float4*>(Arow + k0 + 4);
        float4 bv0 = *reinterpret_cast<const float4*>(Brow + k0);
        float4 bv1 = *reinterpret_cast<const float4*>(Brow + k0 + 4);
        As[kk8 + 0][lrow] = av0.x; As[kk8 + 1][lrow] = av0.y;
        As[kk8 + 2][lrow] = av0.z; As[kk8 + 3][lrow] = av0.w;
        As[kk8 + 4][lrow] = av1.x; As[kk8 + 5][lrow] = av1.y;
        As[kk8 + 6][lrow] = av1.z; As[kk8 + 7][lrow] = av1.w;
        Bs[kk8 + 0][lrow] = bv0.x; Bs[kk8 + 1][lrow] = bv0.y;
        Bs[kk8 + 2][lrow] = bv0.z; Bs[kk8 + 3][lrow] = bv0.w;
        Bs[kk8 + 4][lrow] = bv1.x; Bs[kk8 + 5][lrow] = bv1.y;
        Bs[kk8 + 6][lrow] = bv1.z; Bs[kk8 + 7][lrow] = bv1.w;
        __syncthreads();
        #pragma unroll
        for (int kk = 0; kk < 16; ++kk) {
            float a[8], b[8];
            *reinterpret_cast<float4*>(&a[0]) = *reinterpret_cast<const float4*>(&As[kk][trow]);
            *reinterpret_cast<float4*>(&a[4]) = *reinterpret_cast<const float4*>(&As[kk][trow + 4]);
            *reinterpret_cast<float4*>(&b[0]) = *reinterpret_cast<const float4*>(&Bs[kk][tcol]);
            *reinterpret_cast<float4*>(&b[4]) = *reinterpret_cast<const float4*>(&Bs[kk][tcol + 4]);
            #pragma unroll
            for (int i = 0; i < 8; ++i)
                #pragma unroll
                for (int j = 0; j < 8; ++j) acc[i][j] += a[i] * b[j];
        }
        __syncthreads();
    }
    #pragma unroll
    for (int i = 0; i < 8; ++i) {
        int ri = r0 + trow + i;
        if (ri < ce) {
            float* crow = C + (size_t)(oe + ri) * N + bn + tcol;
            #pragma unroll
            for (int j = 0; j < 8; ++j) crow[j] = acc[i][j];
        }
    }
}

// ---------------- act = bw * silu(g) * u, in place into g ----------------
__global__ __launch_bounds__(256) void act_silu(float* __restrict__ g, const float* __restrict__ u,
                                                const float* __restrict__ bw, int n) {
    int i = blockIdx.x * 256 + threadIdx.x;
    if (i < n) {
        float gv = g[i];
        float s = gv / (1.0f + __expf(-gv));
        g[i] = bw[i >> 10] * s * u[i];
    }
}

// ---------------- Grouped down GEMM with atomic scatter into out ----------------
// act: [P,1024] pair-major. W: [E, 2048, 1024]. out[tok, n] += acc.
__global__ __launch_bounds__(256) void moe_gemm_down(const float* __restrict__ act,
                                                     const float* __restrict__ W,
                                                     float* __restrict__ out,
                                                     const int* __restrict__ btok,
                                                     const int* __restrict__ cnt,
                                                     const int* __restrict__ off) {
    const int N = 2048, K = 1024;
    int e = blockIdx.z;
    int ce = cnt[e];
    int r0 = blockIdx.y * 128;
    if (r0 >= ce) return;
    int oe = off[e];
    __shared__ float As[16][128];
    __shared__ float Bs[16][128];
    int bn = blockIdx.x * 128;
    int tid = threadIdx.x;
    int lrow = tid >> 1;
    int kk8 = (tid & 1) * 8;
    int trow = (tid >> 4) * 8;
    int tcol = (tid & 15) * 8;
    int r = r0 + lrow;
    int rc = (r < ce) ? r : (ce - 1);
    const float* Arow = act + (size_t)(oe + rc) * K + kk8;
    const float* Brow = W + (size_t)e * N * K + (size_t)(bn + lrow) * K + kk8;
    float acc[8][8] = {{0.f}};
    for (int k0 = 0; k0 < K; k0 += 16) {
        float4 av0 = *reinterpret_cast<const float4*>(Arow + k0);
        float4 av1 = *reinterpret_cast<const float4*>(Arow + k0 + 4);
        float4 bv0 = *reinterpret_cast<const float4*>(Brow + k0);
        float4 bv1 = *reinterpret_cast<const float4*>(Brow + k0 + 4);
        As[kk8 + 0][lrow] = av0.x; As[kk8 + 1][lrow] = av0.y;
        As[kk8 + 2][lrow] = av0.z; As[kk8 + 3][lrow] = av0.w;
        As[kk8 + 4][lrow] = av1.x; As[kk8 + 5][lrow] = av1.y;
        As[kk8 + 6][lrow] = av1.z; As[kk8 + 7][lrow] = av1.w;
        Bs[kk8 + 0][lrow] = bv0.x; Bs[kk8 + 1][lrow] = bv0.y;
        Bs[kk8 + 2][lrow] = bv0.z; Bs[kk8 + 3][lrow] = bv0.w;
        Bs[kk8 + 4][lrow] = bv1.x; Bs[kk8 + 5][lrow] = bv1.y;
        Bs[kk8 + 6][lrow] = bv1.z; Bs[kk8 + 7][lrow] = bv1.w;
        __syncthreads();
        #pragma unroll
        for (int kk = 0; kk < 16; ++kk) {
            float a[8], b[8];
            *reinterpret_cast<float4*>(&a[0]) = *reinterpret_cast<const float4*>(&As[kk][trow]);
            *reinterpret_cast<float4*>(&a[4]) = *reinterpret_cast<const float4*>(&As[kk][trow + 4]);
            *reinterpret_cast<float4*>(&b[0]) = *reinterpret_cast<const float4*>(&Bs[kk][tcol]);
            *reinterpret_cast<float4*>(&b[4]) = *reinterpret_cast<const float4*>(&Bs[kk][tcol + 4]);
            #pragma unroll
            for (int i = 0; i < 8; ++i)
                #pragma unroll
                for (int j = 0; j < 8; ++j) acc[i][j] += a[i] * b[j];
        }
        __syncthreads();
    }
    #pragma unroll
    for (int i = 0; i < 8; ++i) {
        int ri = r0 + trow + i;
        if (ri < ce) {
            int tok = btok[oe + ri];
            float* orow = out + (size_t)tok * N + bn + tcol;
            #pragma unroll
            for (int j = 0; j < 8; ++j) atomicAdd(&orow[j], acc[i][j]);
        }
    }
}

// ---------------- silu_mul (shared expert) ----------------
__global__ __launch_bounds__(256) void silu_mul(const float* __restrict__ g, const float* __restrict__ u,
                                                float* __restrict__ o, int n) {
    int i = blockIdx.x * 256 + threadIdx.x;
    if (i < n) { float gv = g[i]; o[i] = gv / (1.0f + __expf(-gv)) * u[i]; }
}

// ---------------- launch ----------------
extern "C" void kernel_launch(void* const* d_in, const int* in_sizes, int n_in,
                              void* d_out, int out_size, void* d_ws, size_t ws_size,
                              hipStream_t stream) {
    (void)in_sizes; (void)n_in; (void)out_size; (void)ws_size;
    const float* x        = (const float*)d_in[0];
    const float* ln1_w    = (const float*)d_in[2];
    const float* ln2_w    = (const float*)d_in[3];
    const float* q_a_w    = (const float*)d_in[4];
    const float* q_a_ln   = (const float*)d_in[5];
    const float* q_b_w    = (const float*)d_in[6];
    const float* kv_a_w   = (const float*)d_in[7];
    const float* kv_a_ln  = (const float*)d_in[8];
    const float* kv_b_w   = (const float*)d_in[9];
    const float* o_w      = (const float*)d_in[10];
    const float* router_w = (const float*)d_in[11];
    const float* router_b = (const float*)d_in[12];
    const float* gate_w   = (const float*)d_in[13];
    const float* up_w     = (const float*)d_in[14];
    const float* down_w   = (const float*)d_in[15];
    const float* sg_w     = (const float*)d_in[16];
    const float* su_w     = (const float*)d_in[17];
    const float* sd_w     = (const float*)d_in[18];

    const size_t T = 2048;
    float* ws = (float*)d_ws;
    // persistent:
    float* x2  = ws;                         // 4,194,304
    float* h2  = x2 + 4194304;               // 4,194,304
    float* big = h2 + 4194304;               // 23,592,960-float scratch region
    // attention phase (within big):
    float* h1     = big;                     // 4,194,304
    float* qa     = h1 + 4194304;            // 1,572,864
    float* kva    = qa + 1572864;            // 1,048,576
    float* qfull  = kva + 1048576;           // 6,291,456
    float* kvfull = qfull + 6291456;         // 10,485,760
    float* ctxb   = h1;                      // h1 dead after q_a/kv_a GEMMs
    // MoE phase (re-uses big; attention intermediates dead):
    float* g = big;                          // 8,388,608  (becomes act in-place)
    float* u = big + 8388608;                // 8,388,608
    int*   topi = (int*)(big + 16777216);    // 8192
    float* topw = (float*)(topi + 8192);     // 8192
    int*   btok = (int*)(topw + 8192);       // 8192
    float* bw   = (float*)(btok + 8192);     // 8192
    int*   cntg = (int*)(bw + 8192);         // 16
    int*   offg = cntg + 16;                 // 16
    float* sg   = big + 16777216 + 65536;    // 2,097,152
    float* su   = sg + 2097152;              // 2,097,152
    float* ash  = su + 2097152;              // 2,097,152  (ends < big+23,592,960)

    // ---- attention half ----
    rmsnorm_f32<<<T, 256, 0, stream>>>(x, ln1_w, h1, 2048);
    gemm_abt128<<<dim3(768 / 128, T / 128), 256, 0, stream>>>(h1, q_a_w, qa, 768, 2048, nullptr);
    gemm_abt128<<<dim3(512 / 128, T / 128), 256, 0, stream>>>(h1, kv_a_w, kva, 512, 2048, nullptr);
    rmsnorm_f32<<<T, 256, 0, stream>>>(qa, q_a_ln, qa, 768);
    rmsnorm_f32<<<T, 256, 0, stream>>>(kva, kv_a_ln, kva, 512);
    gemm_abt128<<<dim3(3072 / 128, T / 128), 256, 0, stream>>>(qa, q_b_w, qfull, 3072, 768, nullptr);
    gemm_abt128<<<dim3(5120 / 128, T / 128), 256, 0, stream>>>(kva, kv_b_w, kvfull, 5120, 512, nullptr);
    rope_kernel<<<(T * 16 * 32) / 256, 256, 0, stream>>>(qfull, kvfull, (int)T);
    attn_kernel<<<T * 16, 128, 0, stream>>>(qfull, kvfull, ctxb, (int)T);
    gemm_abt128<<<dim3(2048 / 128, T / 128), 256, 0, stream>>>(ctxb, o_w, x2, 2048, 2048, x);
    // ---- MoE half ----
    rmsnorm_f32<<<T, 256, 0, stream>>>(x2, ln2_w, h2, 2048);
    router_kernel<<<T, 256, 0, stream>>>(h2, router_w, router_b, topi, topw);
    moe_bucket<<<1, 256, 0, stream>>>(topi, topw, btok, bw, cntg, offg);
    moe_gemm_gu<<<dim3(8, 16, 16), 256, 0, stream>>>(h2, gate_w, g, btok, cntg, offg, 1024, 2048);
    moe_gemm_gu<<<dim3(8, 16, 16), 256, 0, stream>>>(h2, up_w, u, btok, cntg, offg, 1024, 2048);
    act_silu<<<(8192 * 1024) / 256, 256, 0, stream>>>(g, u, bw, 8192 * 1024);
    // shared expert
    gemm_abt128<<<dim3(1024 / 128, T / 128), 256, 0, stream>>>(h2, sg_w, sg, 1024, 2048, nullptr);
    gemm_abt128<<<dim3(1024 / 128, T / 128), 256, 0, stream>>>(h2, su_w, su, 1024, 2048, nullptr);
    silu_mul<<<(T * 1024) / 256, 256, 0, stream>>>(sg, su, ash, (int)(T * 1024));
    // out = x2 + shared_down  (init for atomics)
    gemm_abt128<<<dim3(2048 / 128, T / 128), 256, 0, stream>>>(ash, sd_w, (float*)d_out, 2048, 1024, x2);
    // out += routed down (atomic scatter)
    moe_gemm_down<<<dim3(16, 16, 16), 256, 0, stream>>>(g, down_w, (float*)d_out, btok, cntg, offg);
}